// Round 17
// baseline (107.725 us; speedup 1.0000x reference)
//
#include <hip/hip_runtime.h>

// FFTConv: y[b,d,:] = (h[d] (*) x[b,d])[0:L] + x[b,d]*B[d]
// d_model=1024, L=8192, batch=2, fp32. N=16384 = 16*16*16*4.
// TWO kernels (R9/R10: fusing spills past the immovable 64-VGPR cap).
// bf16-packed LDS zz (64 KB -> 2 blocks/CU, R11). R15 structure (2 block
// barriers + wave fences, fully unrolled, early H-prefetch).
// R16: VALU diet v2 — kernel B measured VALU-issue-bound (VALUBusy 87%).
//  (a) bf16 pack: round(+0x8000) + ONE v_perm_b32 (__builtin_amdgcn_perm,
//      schedulable intrinsic — NOT inline asm, which was R12's mistake).
//      7 ops -> 3 ops per pack.
//  (b) twiddle powers w^L: direct hw sin/cos per power (1 fmul + 2 TRANS-
//      pipe ops, exact argument j*L*2^-k) instead of 15 serial cmuls
//      (90 VALU + long dependency chain).
//   A: Hws[d] = digit-rev spectrum( (FFT(pad(h[d])) + B[d]) / N ), bf16 pairs
//   B: y = stage-exact-inverse( FFT(pad(x0+i*x1)) .* Hws ), natural order

#define L_SEQ   8192
#define N_FFT   16384
#define D_MODEL 1024
#define NTH     1024

// XOR swizzle on u32 index: bijective, stride-1 conflict-free, only touches
// bits [3:0] -> never crosses a 1024-element chunk boundary.
#define SWZ(i) ((i) ^ (((i) >> 4) & 15))

// W16 twiddle constants
#define C16_1 0.92387953251128675613f
#define S16_1 0.38268343236508977173f
#define C16_2 0.70710678118654752440f

// Wave-level LDS fence: waits this wave's DS ops (in-order pipe) and blocks
// compiler reordering. NOT a block barrier.
__device__ __forceinline__ void wave_fence() {
    asm volatile("s_waitcnt lgkmcnt(0)" ::: "memory");
    __builtin_amdgcn_sched_barrier(0);
}

__device__ __forceinline__ float2 cmul(float2 a, float2 b) {
    return make_float2(a.x * b.x - a.y * b.y, a.x * b.y + a.y * b.x);
}
__device__ __forceinline__ float2 cmulc(float2 a, float re, float im) {
    return make_float2(a.x * re - a.y * im, a.x * im + a.y * re);
}

// Hardware sin/cos of (2*pi*rev); exact-argument for rev = (j*L) * 2^-k.
__device__ __forceinline__ float2 hw_cis(float rev) {
    return make_float2(__builtin_amdgcn_cosf(rev), __builtin_amdgcn_sinf(rev));
}

// Pack two floats as bf16 (round-half-up) into one uint: re -> low half,
// im -> high half. 2 adds + 1 v_perm_b32 (selector: D.b0=re.b2, D.b1=re.b3,
// D.b2=im.b2, D.b3=im.b3 -> 0x07060302 with src0=im, src1=re).
__device__ __forceinline__ unsigned bf2pack(float re, float im) {
    const unsigned r = __float_as_uint(re) + 0x8000u;
    const unsigned i = __float_as_uint(im) + 0x8000u;
    return __builtin_amdgcn_perm(i, r, 0x07060302u);
}
__device__ __forceinline__ unsigned bf2pack2(float2 v) { return bf2pack(v.x, v.y); }

__device__ __forceinline__ float2 bf2unpack(unsigned p) {
    return make_float2(__uint_as_float(p << 16), __uint_as_float(p & 0xffff0000u));
}

// Radix-4 butterfly, in place. S=-1 forward DFT, S=+1 inverse (unscaled).
template <int S>
__device__ __forceinline__ void bfly4(float2& r0, float2& r1, float2& r2, float2& r3) {
    const float2 t0 = make_float2(r0.x + r2.x, r0.y + r2.y);
    const float2 t1 = make_float2(r0.x - r2.x, r0.y - r2.y);
    const float2 t2 = make_float2(r1.x + r3.x, r1.y + r3.y);
    const float2 t3 = make_float2(r1.x - r3.x, r1.y - r3.y);
    r0 = make_float2(t0.x + t2.x, t0.y + t2.y);
    r2 = make_float2(t0.x - t2.x, t0.y - t2.y);
    if (S < 0) {
        r1 = make_float2(t1.x + t3.y, t1.y - t3.x);   // t1 - i*t3
        r3 = make_float2(t1.x - t3.y, t1.y + t3.x);   // t1 + i*t3
    } else {
        r1 = make_float2(t1.x - t3.y, t1.y + t3.x);
        r3 = make_float2(t1.x + t3.y, t1.y - t3.x);
    }
}

// W16^(m0*k1) twiddles between the two radix-4 levels of a DFT16 (slot m0+4k1).
template <int S>
__device__ __forceinline__ void dft16_mid_twiddle(float2 a[16]) {
    const float s = (float)S;
    a[5]  = cmulc(a[5],   C16_1,  s * S16_1);                   // e1
    a[9]  = cmulc(a[9],   C16_2,  s * C16_2);                   // e2
    a[13] = cmulc(a[13],  S16_1,  s * C16_1);                   // e3
    a[6]  = cmulc(a[6],   C16_2,  s * C16_2);                   // e2
    a[10] = make_float2(-s * a[10].y, s * a[10].x);             // e4 = S*i
    a[14] = cmulc(a[14], -C16_2,  s * C16_2);                   // e6
    a[7]  = cmulc(a[7],   S16_1,  s * C16_1);                   // e3
    a[11] = cmulc(a[11], -C16_2,  s * C16_2);                   // e6
    a[15] = cmulc(a[15], -C16_1, -s * S16_1);                   // e9
}

// In-register 16-point DFT. Input: logical m at slot m. Output: logical
// A[k1+4k2] at slot 4k1+k2 (digit-swapped). All indices compile-time.
template <int S>
__device__ __forceinline__ void dft16(float2 a[16]) {
    bfly4<S>(a[0], a[4], a[8],  a[12]);
    bfly4<S>(a[1], a[5], a[9],  a[13]);
    bfly4<S>(a[2], a[6], a[10], a[14]);
    bfly4<S>(a[3], a[7], a[11], a[15]);
    dft16_mid_twiddle<S>(a);
    bfly4<S>(a[0],  a[1],  a[2],  a[3]);
    bfly4<S>(a[4],  a[5],  a[6],  a[7]);
    bfly4<S>(a[8],  a[9],  a[10], a[11]);
    bfly4<S>(a[12], a[13], a[14], a[15]);
}

// Inner radix-4 level of DFT16 when inputs m1=2,3 are zero (padded signal):
// DFT4 of (p,q,0,0) -> X[k1] = p + q*W4^(S*k1), slot c+4k1.
template <int S>
__device__ __forceinline__ void inner4_halfzero(float2 a[16]) {
#pragma unroll
    for (int c = 0; c < 4; ++c) {
        const float2 p = a[c], q = a[c + 4];
        a[c]      = make_float2(p.x + q.x, p.y + q.y);
        a[c + 8]  = make_float2(p.x - q.x, p.y - q.y);
        if (S < 0) {
            a[c + 4]  = make_float2(p.x + q.y, p.y - q.x);   // p - i*q
            a[c + 12] = make_float2(p.x - q.y, p.y + q.x);   // p + i*q
        } else {
            a[c + 4]  = make_float2(p.x - q.y, p.y + q.x);
            a[c + 12] = make_float2(p.x + q.y, p.y - q.x);
        }
    }
}

// Shared tail of the fused forward load-stage: mid twiddle, outer bfly4,
// external twiddles W^(-tid*L) via direct cis (exact: tid*L < 2^14),
// digit-swapped scatter to zz. Cross-chunk scatter -> __syncthreads inside.
__device__ __forceinline__ void fwd_stage1_finish(unsigned* __restrict__ zz,
                                                  const int tid, float2 a[16]) {
    dft16_mid_twiddle<-1>(a);
    bfly4<-1>(a[0],  a[1],  a[2],  a[3]);
    bfly4<-1>(a[4],  a[5],  a[6],  a[7]);
    bfly4<-1>(a[8],  a[9],  a[10], a[11]);
    bfly4<-1>(a[12], a[13], a[14], a[15]);
    const float fj = (float)tid;
    zz[SWZ(tid)] = bf2pack2(a[0]);
#pragma unroll
    for (int L = 1; L < 16; ++L) {
        const int P = ((L & 3) << 2) | (L >> 2);   // slot of logical L
        const float2 wL = hw_cis(fj * (-(float)L / 16384.0f));
        zz[SWZ(tid + (L << 10))] = bf2pack2(cmul(a[P], wL));
    }
    __syncthreads();
}

// One LDS radix-16 stage, span q = 1<<LQ (6 or 2) — addressing is
// WAVE-PRIVATE to chunk (tid>>6): no block barrier, caller supplies fence.
// Twiddle powers via direct cis: rev = j*L*2^-(LQ+4), exact argument.
template <int S, int LQ>
__device__ __forceinline__ void fft16_stage_bf(unsigned* __restrict__ zz, const int tid) {
    const int q = 1 << LQ;
    const int j = tid & (q - 1);
    const int base = ((tid >> LQ) << (LQ + 4)) | j;
    const float fj = (float)j;
    float2 a[16];
    if (S < 0) {
#pragma unroll
        for (int m = 0; m < 16; ++m) a[m] = bf2unpack(zz[SWZ(base + m * q)]);
        dft16<S>(a);
        zz[SWZ(base)] = bf2pack2(a[0]);
#pragma unroll
        for (int L = 1; L < 16; ++L) {
            const int P = ((L & 3) << 2) | (L >> 2);
            const float2 wL = hw_cis(fj * (-(float)L / (float)(1 << (LQ + 4))));
            zz[SWZ(base + L * q)] = bf2pack2(cmul(a[P], wL));
        }
    } else {
#pragma unroll
        for (int k = 0; k < 16; ++k) a[k] = bf2unpack(zz[SWZ(base + k * q)]);
#pragma unroll
        for (int k = 1; k < 16; ++k) {
            const float2 wk = hw_cis(fj * ((float)k / (float)(1 << (LQ + 4))));
            a[k] = cmul(a[k], wk);
        }
        dft16<S>(a);
#pragma unroll
        for (int M = 0; M < 16; ++M) {
            const int P = ((M & 3) << 2) | (M >> 2);
            zz[SWZ(base + M * q)] = bf2pack2(a[P]);
        }
    }
}

// Kernel A: filter spectrum -> Hws (packed bf16), digit-reversed order,
// (H + B)/N folded.
__global__ void __launch_bounds__(NTH) fftconv_filter_kernel(
        const float* __restrict__ h, const float* __restrict__ Bg,
        unsigned* __restrict__ Hws) {
    extern __shared__ unsigned zz[];
    const int d = blockIdx.x;
    const int tid = threadIdx.x;
    const int w = tid >> 6, l = tid & 63;
    const float invn = 1.0f / (float)N_FFT;
    const float Bs = Bg[d] * invn;

    // fused: load h (upper half zero) + forward stage 1 (span 1024)
    {
        const float* hrow = h + (size_t)d * L_SEQ;
        float2 a[16];
#pragma unroll
        for (int m = 0; m < 8; ++m)
            a[m] = make_float2(hrow[tid + (m << 10)], 0.0f);
        inner4_halfzero<-1>(a);
        fwd_stage1_finish(zz, tid, a);   // __syncthreads inside
    }
    fft16_stage_bf<-1, 6>(zz, tid);
    wave_fence();
    fft16_stage_bf<-1, 2>(zz, tid);
    wave_fence();

    // final forward stage (radix-4, q=1, w==1) in regs; wave-private quads
    unsigned* Hrow = Hws + (size_t)d * N_FFT;
#pragma unroll
    for (int r = 0; r < 4; ++r) {
        const int qi = (w << 8) + (r << 6) + l;
        const int b = qi << 2;
        float2 a0 = bf2unpack(zz[SWZ(b)]);
        float2 a1 = bf2unpack(zz[SWZ(b + 1)]);
        float2 a2 = bf2unpack(zz[SWZ(b + 2)]);
        float2 a3 = bf2unpack(zz[SWZ(b + 3)]);
        bfly4<-1>(a0, a1, a2, a3);
        ((uint4*)Hrow)[qi] = make_uint4(
            bf2pack(a0.x * invn + Bs, a0.y * invn),
            bf2pack(a1.x * invn + Bs, a1.y * invn),
            bf2pack(a2.x * invn + Bs, a2.y * invn),
            bf2pack(a3.x * invn + Bs, a3.y * invn));
    }
}

// Kernel B: y = inverse( FFT(x0 + i*x1) .* Hws ), natural-order output.
// Two block barriers total; interior phases wave-private with fences.
__global__ void __launch_bounds__(NTH) fftconv_conv_kernel(
        const float* __restrict__ x, const unsigned* __restrict__ Hws,
        float* __restrict__ y) {
    extern __shared__ unsigned zz[];
    const int d = blockIdx.x;
    const int tid = threadIdx.x;
    const int w = tid >> 6, l = tid & 63;

    const float* x0 = x + (size_t)d * L_SEQ;
    const float* x1 = x + (size_t)(D_MODEL + d) * L_SEQ;

    // fused: load x0+i*x1 (upper half zero) + forward stage 1 (span 1024)
    {
        float2 a[16];
#pragma unroll
        for (int m = 0; m < 8; ++m) {
            const int idx = tid + (m << 10);
            a[m] = make_float2(x0[idx], x1[idx]);
        }
        inner4_halfzero<-1>(a);
        fwd_stage1_finish(zz, tid, a);   // __syncthreads inside
    }

    // prefetch this wave's 16 H bins (4x uint4); vmcnt stays outstanding
    // across both interior forward stages (no barrier in the way).
    const uint4* Hp = (const uint4*)(Hws + (size_t)d * N_FFT);
    const int qbase = (w << 8) + l;
    const uint4 hp0 = Hp[qbase];
    const uint4 hp1 = Hp[qbase + 64];
    const uint4 hp2 = Hp[qbase + 128];
    const uint4 hp3 = Hp[qbase + 192];

    fft16_stage_bf<-1, 6>(zz, tid);
    wave_fence();
    fft16_stage_bf<-1, 2>(zz, tid);
    wave_fence();

    // fused middle: fwd radix-4 (w=1) -> pointwise Hws -> inv radix-4 (w=1)
#pragma unroll
    for (int r = 0; r < 4; ++r) {
        const int b = ((w << 8) + (r << 6) + l) << 2;
        const int p0 = SWZ(b), p1 = SWZ(b + 1), p2 = SWZ(b + 2), p3 = SWZ(b + 3);
        float2 a0 = bf2unpack(zz[p0]);
        float2 a1 = bf2unpack(zz[p1]);
        float2 a2 = bf2unpack(zz[p2]);
        float2 a3 = bf2unpack(zz[p3]);
        bfly4<-1>(a0, a1, a2, a3);
        const uint4 hp = (r == 0) ? hp0 : (r == 1) ? hp1 : (r == 2) ? hp2 : hp3;
        a0 = cmul(a0, bf2unpack(hp.x));
        a1 = cmul(a1, bf2unpack(hp.y));
        a2 = cmul(a2, bf2unpack(hp.z));
        a3 = cmul(a3, bf2unpack(hp.w));
        bfly4<+1>(a0, a1, a2, a3);
        zz[p0] = bf2pack2(a0);
        zz[p1] = bf2pack2(a1);
        zz[p2] = bf2pack2(a2);
        zz[p3] = bf2pack2(a3);
    }
    wave_fence();

    fft16_stage_bf<+1, 2>(zz, tid);
    wave_fence();
    fft16_stage_bf<+1, 6>(zz, tid);
    __syncthreads();   // final gather crosses chunks

    // fused: final inverse stage (span 1024) + store of outputs [0, 8192)
    {
        float2 a[16];
#pragma unroll
        for (int k = 0; k < 16; ++k) a[k] = bf2unpack(zz[SWZ(tid + (k << 10))]);
        const float fj = (float)tid;
#pragma unroll
        for (int k = 1; k < 16; ++k) {
            const float2 wk = hw_cis(fj * ((float)k / 16384.0f));
            a[k] = cmul(a[k], wk);
        }
        bfly4<+1>(a[0], a[4], a[8],  a[12]);
        bfly4<+1>(a[1], a[5], a[9],  a[13]);
        bfly4<+1>(a[2], a[6], a[10], a[14]);
        bfly4<+1>(a[3], a[7], a[11], a[15]);
        dft16_mid_twiddle<+1>(a);
        float* y0 = y + (size_t)d * L_SEQ;
        float* y1 = y + (size_t)(D_MODEL + d) * L_SEQ;
        // outer bfly4, partial: only logical outputs M=g, g+4 (< 8192 kept)
#pragma unroll
        for (int g = 0; g < 4; ++g) {
            const float2 b0 = a[4*g], b1 = a[4*g+1], b2 = a[4*g+2], b3 = a[4*g+3];
            const float2 t0 = make_float2(b0.x + b2.x, b0.y + b2.y);
            const float2 t1 = make_float2(b0.x - b2.x, b0.y - b2.y);
            const float2 t2 = make_float2(b1.x + b3.x, b1.y + b3.y);
            const float2 t3 = make_float2(b1.x - b3.x, b1.y - b3.y);
            const float2 r0 = make_float2(t0.x + t2.x, t0.y + t2.y);   // M=g
            const float2 r1 = make_float2(t1.x - t3.y, t1.y + t3.x);   // M=g+4 (S=+1)
            const int q0 = tid + (g << 10);
            const int q1 = tid + ((g + 4) << 10);
            y0[q0] = r0.x; y1[q0] = r0.y;
            y0[q1] = r1.x; y1[q1] = r1.y;
        }
    }
}

extern "C" void kernel_launch(void* const* d_in, const int* in_sizes, int n_in,
                              void* d_out, int out_size, void* d_ws, size_t ws_size,
                              hipStream_t stream) {
    const float* h = (const float*)d_in[0];   // (1024, 8192)
    const float* x = (const float*)d_in[1];   // (2, 1024, 8192)
    const float* B = (const float*)d_in[2];   // (1024, 1)
    float* y = (float*)d_out;                 // (2, 1024, 8192)
    unsigned* Hws = (unsigned*)d_ws;          // 1024 x 16384 packed bf16 = 67 MB

    const size_t lds_bytes = (size_t)N_FFT * sizeof(unsigned);  // 64 KB

    fftconv_filter_kernel<<<dim3(D_MODEL), dim3(NTH), lds_bytes, stream>>>(h, B, Hws);
    fftconv_conv_kernel<<<dim3(D_MODEL), dim3(NTH), lds_bytes, stream>>>(x, Hws, y);
}

// Round 18
// 94.928 us; speedup vs baseline: 1.1348x; 1.1348x over previous
//
#include <hip/hip_runtime.h>

// FFTConv: y[b,d,:] = (h[d] (*) x[b,d])[0:L] + x[b,d]*B[d]
// d_model=1024, L=8192, batch=2, fp32. N=16384 = 16*16*16*4.
// TWO kernels (R9/R10: fusing spills past the immovable 64-VGPR cap).
// bf16-packed LDS zz (64 KB -> 2 blocks/CU, R11). R15 structure (2 block
// barriers + wave fences, fully unrolled, early H-prefetch, cmul-chain
// twiddles — R16 proved TRANS-pipe per-power cis regresses: quarter-rate).
// R17 = R15 + ONE isolated change: bf16 pack via +0x8000 round and a single
// v_perm_b32 (__builtin_amdgcn_perm, schedulable intrinsic): 7 -> 3 ops per
// pack in a measured VALU-issue-bound kernel (VALUBusy 87%).
//   A: Hws[d] = digit-rev spectrum( (FFT(pad(h[d])) + B[d]) / N ), bf16 pairs
//   B: y = stage-exact-inverse( FFT(pad(x0+i*x1)) .* Hws ), natural order

#define L_SEQ   8192
#define N_FFT   16384
#define D_MODEL 1024
#define NTH     1024

// XOR swizzle on u32 index: bijective, stride-1 conflict-free, only touches
// bits [3:0] -> never crosses a 1024-element chunk boundary.
#define SWZ(i) ((i) ^ (((i) >> 4) & 15))

// W16 twiddle constants
#define C16_1 0.92387953251128675613f
#define S16_1 0.38268343236508977173f
#define C16_2 0.70710678118654752440f

// Wave-level LDS fence: waits this wave's DS ops (in-order pipe) and blocks
// compiler reordering. NOT a block barrier.
__device__ __forceinline__ void wave_fence() {
    asm volatile("s_waitcnt lgkmcnt(0)" ::: "memory");
    __builtin_amdgcn_sched_barrier(0);
}

__device__ __forceinline__ float2 cmul(float2 a, float2 b) {
    return make_float2(a.x * b.x - a.y * b.y, a.x * b.y + a.y * b.x);
}
__device__ __forceinline__ float2 cmulc(float2 a, float re, float im) {
    return make_float2(a.x * re - a.y * im, a.x * im + a.y * re);
}

// Hardware sin/cos of (2*pi*rev); exact-argument for rev = j * 2^-k.
// Used ONCE per stage (w1 seed); powers via cmul chain (full-rate VALU).
__device__ __forceinline__ float2 hw_cis(float rev) {
    return make_float2(__builtin_amdgcn_cosf(rev), __builtin_amdgcn_sinf(rev));
}

// Pack two floats as bf16 (round-half-up) into one uint: re -> low half,
// im -> high half. 2 adds + 1 v_perm_b32 (D.b0=re.b2, D.b1=re.b3,
// D.b2=im.b2, D.b3=im.b3 -> selector 0x07060302, src0=im, src1=re).
__device__ __forceinline__ unsigned bf2pack(float re, float im) {
    const unsigned r = __float_as_uint(re) + 0x8000u;
    const unsigned i = __float_as_uint(im) + 0x8000u;
    return __builtin_amdgcn_perm(i, r, 0x07060302u);
}
__device__ __forceinline__ unsigned bf2pack2(float2 v) { return bf2pack(v.x, v.y); }

__device__ __forceinline__ float2 bf2unpack(unsigned p) {
    return make_float2(__uint_as_float(p << 16), __uint_as_float(p & 0xffff0000u));
}

// Radix-4 butterfly, in place. S=-1 forward DFT, S=+1 inverse (unscaled).
template <int S>
__device__ __forceinline__ void bfly4(float2& r0, float2& r1, float2& r2, float2& r3) {
    const float2 t0 = make_float2(r0.x + r2.x, r0.y + r2.y);
    const float2 t1 = make_float2(r0.x - r2.x, r0.y - r2.y);
    const float2 t2 = make_float2(r1.x + r3.x, r1.y + r3.y);
    const float2 t3 = make_float2(r1.x - r3.x, r1.y - r3.y);
    r0 = make_float2(t0.x + t2.x, t0.y + t2.y);
    r2 = make_float2(t0.x - t2.x, t0.y - t2.y);
    if (S < 0) {
        r1 = make_float2(t1.x + t3.y, t1.y - t3.x);   // t1 - i*t3
        r3 = make_float2(t1.x - t3.y, t1.y + t3.x);   // t1 + i*t3
    } else {
        r1 = make_float2(t1.x - t3.y, t1.y + t3.x);
        r3 = make_float2(t1.x + t3.y, t1.y - t3.x);
    }
}

// W16^(m0*k1) twiddles between the two radix-4 levels of a DFT16 (slot m0+4k1).
template <int S>
__device__ __forceinline__ void dft16_mid_twiddle(float2 a[16]) {
    const float s = (float)S;
    a[5]  = cmulc(a[5],   C16_1,  s * S16_1);                   // e1
    a[9]  = cmulc(a[9],   C16_2,  s * C16_2);                   // e2
    a[13] = cmulc(a[13],  S16_1,  s * C16_1);                   // e3
    a[6]  = cmulc(a[6],   C16_2,  s * C16_2);                   // e2
    a[10] = make_float2(-s * a[10].y, s * a[10].x);             // e4 = S*i
    a[14] = cmulc(a[14], -C16_2,  s * C16_2);                   // e6
    a[7]  = cmulc(a[7],   S16_1,  s * C16_1);                   // e3
    a[11] = cmulc(a[11], -C16_2,  s * C16_2);                   // e6
    a[15] = cmulc(a[15], -C16_1, -s * S16_1);                   // e9
}

// In-register 16-point DFT. Input: logical m at slot m. Output: logical
// A[k1+4k2] at slot 4k1+k2 (digit-swapped). All indices compile-time.
template <int S>
__device__ __forceinline__ void dft16(float2 a[16]) {
    bfly4<S>(a[0], a[4], a[8],  a[12]);
    bfly4<S>(a[1], a[5], a[9],  a[13]);
    bfly4<S>(a[2], a[6], a[10], a[14]);
    bfly4<S>(a[3], a[7], a[11], a[15]);
    dft16_mid_twiddle<S>(a);
    bfly4<S>(a[0],  a[1],  a[2],  a[3]);
    bfly4<S>(a[4],  a[5],  a[6],  a[7]);
    bfly4<S>(a[8],  a[9],  a[10], a[11]);
    bfly4<S>(a[12], a[13], a[14], a[15]);
}

// Inner radix-4 level of DFT16 when inputs m1=2,3 are zero (padded signal):
// DFT4 of (p,q,0,0) -> X[k1] = p + q*W4^(S*k1), slot c+4k1.
template <int S>
__device__ __forceinline__ void inner4_halfzero(float2 a[16]) {
#pragma unroll
    for (int c = 0; c < 4; ++c) {
        const float2 p = a[c], q = a[c + 4];
        a[c]      = make_float2(p.x + q.x, p.y + q.y);
        a[c + 8]  = make_float2(p.x - q.x, p.y - q.y);
        if (S < 0) {
            a[c + 4]  = make_float2(p.x + q.y, p.y - q.x);   // p - i*q
            a[c + 12] = make_float2(p.x - q.y, p.y + q.x);   // p + i*q
        } else {
            a[c + 4]  = make_float2(p.x - q.y, p.y + q.x);
            a[c + 12] = make_float2(p.x + q.y, p.y - q.x);
        }
    }
}

// Shared tail of the fused forward load-stage: mid twiddle, outer bfly4,
// external twiddle chain W^(-j*L) (j = tid), digit-swapped scatter to zz.
// Cross-chunk scatter -> __syncthreads kept inside.
__device__ __forceinline__ void fwd_stage1_finish(unsigned* __restrict__ zz,
                                                  const int tid, float2 a[16]) {
    dft16_mid_twiddle<-1>(a);
    bfly4<-1>(a[0],  a[1],  a[2],  a[3]);
    bfly4<-1>(a[4],  a[5],  a[6],  a[7]);
    bfly4<-1>(a[8],  a[9],  a[10], a[11]);
    bfly4<-1>(a[12], a[13], a[14], a[15]);
    const float2 w1 = hw_cis(-(float)tid * (1.0f / 16384.0f));
    zz[SWZ(tid)] = bf2pack2(a[0]);
    float2 wc = w1;
#pragma unroll
    for (int L = 1; L < 16; ++L) {
        const int P = ((L & 3) << 2) | (L >> 2);   // slot of logical L
        zz[SWZ(tid + (L << 10))] = bf2pack2(cmul(a[P], wc));
        wc = cmul(wc, w1);
    }
    __syncthreads();
}

// One LDS radix-16 stage, span q = 1<<LQ (6 or 2) — addressing is
// WAVE-PRIVATE to chunk (tid>>6): no block barrier, caller supplies fence.
template <int S, int LQ>
__device__ __forceinline__ void fft16_stage_bf(unsigned* __restrict__ zz, const int tid) {
    const int q = 1 << LQ;
    const int j = tid & (q - 1);
    const int base = ((tid >> LQ) << (LQ + 4)) | j;
    const float2 w1 = hw_cis((float)S * (float)j / (float)(1 << (LQ + 4)));
    float2 a[16];
    if (S < 0) {
#pragma unroll
        for (int m = 0; m < 16; ++m) a[m] = bf2unpack(zz[SWZ(base + m * q)]);
        dft16<S>(a);
        zz[SWZ(base)] = bf2pack2(a[0]);
        float2 wc = w1;
#pragma unroll
        for (int L = 1; L < 16; ++L) {
            const int P = ((L & 3) << 2) | (L >> 2);
            zz[SWZ(base + L * q)] = bf2pack2(cmul(a[P], wc));
            wc = cmul(wc, w1);
        }
    } else {
#pragma unroll
        for (int k = 0; k < 16; ++k) a[k] = bf2unpack(zz[SWZ(base + k * q)]);
        float2 wc = w1;
#pragma unroll
        for (int k = 1; k < 16; ++k) { a[k] = cmul(a[k], wc); wc = cmul(wc, w1); }
        dft16<S>(a);
#pragma unroll
        for (int M = 0; M < 16; ++M) {
            const int P = ((M & 3) << 2) | (M >> 2);
            zz[SWZ(base + M * q)] = bf2pack2(a[P]);
        }
    }
}

// Kernel A: filter spectrum -> Hws (packed bf16), digit-reversed order,
// (H + B)/N folded.
__global__ void __launch_bounds__(NTH) fftconv_filter_kernel(
        const float* __restrict__ h, const float* __restrict__ Bg,
        unsigned* __restrict__ Hws) {
    extern __shared__ unsigned zz[];
    const int d = blockIdx.x;
    const int tid = threadIdx.x;
    const int w = tid >> 6, l = tid & 63;
    const float invn = 1.0f / (float)N_FFT;
    const float Bs = Bg[d] * invn;

    // fused: load h (upper half zero) + forward stage 1 (span 1024)
    {
        const float* hrow = h + (size_t)d * L_SEQ;
        float2 a[16];
#pragma unroll
        for (int m = 0; m < 8; ++m)
            a[m] = make_float2(hrow[tid + (m << 10)], 0.0f);
        inner4_halfzero<-1>(a);
        fwd_stage1_finish(zz, tid, a);   // __syncthreads inside
    }
    fft16_stage_bf<-1, 6>(zz, tid);
    wave_fence();
    fft16_stage_bf<-1, 2>(zz, tid);
    wave_fence();

    // final forward stage (radix-4, q=1, w==1) in regs; wave-private quads
    unsigned* Hrow = Hws + (size_t)d * N_FFT;
#pragma unroll
    for (int r = 0; r < 4; ++r) {
        const int qi = (w << 8) + (r << 6) + l;
        const int b = qi << 2;
        float2 a0 = bf2unpack(zz[SWZ(b)]);
        float2 a1 = bf2unpack(zz[SWZ(b + 1)]);
        float2 a2 = bf2unpack(zz[SWZ(b + 2)]);
        float2 a3 = bf2unpack(zz[SWZ(b + 3)]);
        bfly4<-1>(a0, a1, a2, a3);
        ((uint4*)Hrow)[qi] = make_uint4(
            bf2pack(a0.x * invn + Bs, a0.y * invn),
            bf2pack(a1.x * invn + Bs, a1.y * invn),
            bf2pack(a2.x * invn + Bs, a2.y * invn),
            bf2pack(a3.x * invn + Bs, a3.y * invn));
    }
}

// Kernel B: y = inverse( FFT(x0 + i*x1) .* Hws ), natural-order output.
// Two block barriers total; interior phases wave-private with fences.
__global__ void __launch_bounds__(NTH) fftconv_conv_kernel(
        const float* __restrict__ x, const unsigned* __restrict__ Hws,
        float* __restrict__ y) {
    extern __shared__ unsigned zz[];
    const int d = blockIdx.x;
    const int tid = threadIdx.x;
    const int w = tid >> 6, l = tid & 63;

    const float* x0 = x + (size_t)d * L_SEQ;
    const float* x1 = x + (size_t)(D_MODEL + d) * L_SEQ;

    // fused: load x0+i*x1 (upper half zero) + forward stage 1 (span 1024)
    {
        float2 a[16];
#pragma unroll
        for (int m = 0; m < 8; ++m) {
            const int idx = tid + (m << 10);
            a[m] = make_float2(x0[idx], x1[idx]);
        }
        inner4_halfzero<-1>(a);
        fwd_stage1_finish(zz, tid, a);   // __syncthreads inside
    }

    // prefetch this wave's 16 H bins (4x uint4); vmcnt stays outstanding
    // across both interior forward stages (no barrier in the way).
    const uint4* Hp = (const uint4*)(Hws + (size_t)d * N_FFT);
    const int qbase = (w << 8) + l;
    const uint4 hp0 = Hp[qbase];
    const uint4 hp1 = Hp[qbase + 64];
    const uint4 hp2 = Hp[qbase + 128];
    const uint4 hp3 = Hp[qbase + 192];

    fft16_stage_bf<-1, 6>(zz, tid);
    wave_fence();
    fft16_stage_bf<-1, 2>(zz, tid);
    wave_fence();

    // fused middle: fwd radix-4 (w=1) -> pointwise Hws -> inv radix-4 (w=1)
#pragma unroll
    for (int r = 0; r < 4; ++r) {
        const int b = ((w << 8) + (r << 6) + l) << 2;
        const int p0 = SWZ(b), p1 = SWZ(b + 1), p2 = SWZ(b + 2), p3 = SWZ(b + 3);
        float2 a0 = bf2unpack(zz[p0]);
        float2 a1 = bf2unpack(zz[p1]);
        float2 a2 = bf2unpack(zz[p2]);
        float2 a3 = bf2unpack(zz[p3]);
        bfly4<-1>(a0, a1, a2, a3);
        const uint4 hp = (r == 0) ? hp0 : (r == 1) ? hp1 : (r == 2) ? hp2 : hp3;
        a0 = cmul(a0, bf2unpack(hp.x));
        a1 = cmul(a1, bf2unpack(hp.y));
        a2 = cmul(a2, bf2unpack(hp.z));
        a3 = cmul(a3, bf2unpack(hp.w));
        bfly4<+1>(a0, a1, a2, a3);
        zz[p0] = bf2pack2(a0);
        zz[p1] = bf2pack2(a1);
        zz[p2] = bf2pack2(a2);
        zz[p3] = bf2pack2(a3);
    }
    wave_fence();

    fft16_stage_bf<+1, 2>(zz, tid);
    wave_fence();
    fft16_stage_bf<+1, 6>(zz, tid);
    __syncthreads();   // final gather crosses chunks

    // fused: final inverse stage (span 1024) + store of outputs [0, 8192)
    {
        float2 a[16];
#pragma unroll
        for (int k = 0; k < 16; ++k) a[k] = bf2unpack(zz[SWZ(tid + (k << 10))]);
        const float2 w1 = hw_cis((float)tid * (1.0f / 16384.0f));
        float2 wc = w1;
#pragma unroll
        for (int k = 1; k < 16; ++k) { a[k] = cmul(a[k], wc); wc = cmul(wc, w1); }
        bfly4<+1>(a[0], a[4], a[8],  a[12]);
        bfly4<+1>(a[1], a[5], a[9],  a[13]);
        bfly4<+1>(a[2], a[6], a[10], a[14]);
        bfly4<+1>(a[3], a[7], a[11], a[15]);
        dft16_mid_twiddle<+1>(a);
        float* y0 = y + (size_t)d * L_SEQ;
        float* y1 = y + (size_t)(D_MODEL + d) * L_SEQ;
        // outer bfly4, partial: only logical outputs M=g, g+4 (< 8192 kept)
#pragma unroll
        for (int g = 0; g < 4; ++g) {
            const float2 b0 = a[4*g], b1 = a[4*g+1], b2 = a[4*g+2], b3 = a[4*g+3];
            const float2 t0 = make_float2(b0.x + b2.x, b0.y + b2.y);
            const float2 t1 = make_float2(b0.x - b2.x, b0.y - b2.y);
            const float2 t2 = make_float2(b1.x + b3.x, b1.y + b3.y);
            const float2 t3 = make_float2(b1.x - b3.x, b1.y - b3.y);
            const float2 r0 = make_float2(t0.x + t2.x, t0.y + t2.y);   // M=g
            const float2 r1 = make_float2(t1.x - t3.y, t1.y + t3.x);   // M=g+4 (S=+1)
            const int q0 = tid + (g << 10);
            const int q1 = tid + ((g + 4) << 10);
            y0[q0] = r0.x; y1[q0] = r0.y;
            y0[q1] = r1.x; y1[q1] = r1.y;
        }
    }
}

extern "C" void kernel_launch(void* const* d_in, const int* in_sizes, int n_in,
                              void* d_out, int out_size, void* d_ws, size_t ws_size,
                              hipStream_t stream) {
    const float* h = (const float*)d_in[0];   // (1024, 8192)
    const float* x = (const float*)d_in[1];   // (2, 1024, 8192)
    const float* B = (const float*)d_in[2];   // (1024, 1)
    float* y = (float*)d_out;                 // (2, 1024, 8192)
    unsigned* Hws = (unsigned*)d_ws;          // 1024 x 16384 packed bf16 = 67 MB

    const size_t lds_bytes = (size_t)N_FFT * sizeof(unsigned);  // 64 KB

    fftconv_filter_kernel<<<dim3(D_MODEL), dim3(NTH), lds_bytes, stream>>>(h, B, Hws);
    fftconv_conv_kernel<<<dim3(D_MODEL), dim3(NTH), lds_bytes, stream>>>(x, Hws, y);
}

// Round 19
// 92.546 us; speedup vs baseline: 1.1640x; 1.0257x over previous
//
#include <hip/hip_runtime.h>

// FFTConv: y[b,d,:] = (h[d] (*) x[b,d])[0:L] + x[b,d]*B[d]
// d_model=1024, L=8192, batch=2, fp32. N=16384 = 16*16*16*4.
// TWO kernels (R9/R10: fusing spills past the immovable 64-VGPR cap).
// bf16-packed LDS zz (R11), R15 structure, perm-pack (R17).
// R18: PADDED LDS LAYOUT replaces the XOR swizzle. P(i) = i + (i>>5).
// XOR swizzle can't fold into ds offset immediates (XOR != add), so every
// LDS access paid 3-4 VALU of index math (~100+/stage — the gap between
// op-count model 28us and measured 69us issue). With padding, every access
// pattern here is pbase + compile-time-const (no-carry proven per pattern):
//   LQ=6: pbase + 66m | LQ=2: pbase + 4k + (k>>3) | span-1024: pb1 + 1056L
//   quads: 4qi + (qi>>3) + e
// Banks: 2 lanes/bank everywhere (free, m136). LDS = 67.6 KB -> still
// 2 blocks/CU.
//   A: Hws[d] = digit-rev spectrum( (FFT(pad(h[d])) + B[d]) / N ), bf16 pairs
//   B: y = stage-exact-inverse( FFT(pad(x0+i*x1)) .* Hws ), natural order

#define L_SEQ   8192
#define N_FFT   16384
#define D_MODEL 1024
#define NTH     1024
#define LDS_U32 (N_FFT + (N_FFT >> 5))   // 16896 u32 = 67.6 KB

// W16 twiddle constants
#define C16_1 0.92387953251128675613f
#define S16_1 0.38268343236508977173f
#define C16_2 0.70710678118654752440f

// Wave-level LDS fence: waits this wave's DS ops (in-order pipe) and blocks
// compiler reordering. NOT a block barrier.
__device__ __forceinline__ void wave_fence() {
    asm volatile("s_waitcnt lgkmcnt(0)" ::: "memory");
    __builtin_amdgcn_sched_barrier(0);
}

__device__ __forceinline__ float2 cmul(float2 a, float2 b) {
    return make_float2(a.x * b.x - a.y * b.y, a.x * b.y + a.y * b.x);
}
__device__ __forceinline__ float2 cmulc(float2 a, float re, float im) {
    return make_float2(a.x * re - a.y * im, a.x * im + a.y * re);
}

// Hardware sin/cos of (2*pi*rev); exact-argument for rev = j * 2^-k.
// Used ONCE per stage (w1 seed); powers via cmul chain (full-rate VALU;
// R16 proved per-power TRANS-pipe cis regresses — quarter-rate pipe).
__device__ __forceinline__ float2 hw_cis(float rev) {
    return make_float2(__builtin_amdgcn_cosf(rev), __builtin_amdgcn_sinf(rev));
}

// Pack two floats as bf16 (round-half-up) into one uint: re -> low half,
// im -> high half. 2 adds + 1 v_perm_b32 (selector 0x07060302, src0=im,
// src1=re). Schedulable intrinsic (R12's inline-asm variant blocked sched).
__device__ __forceinline__ unsigned bf2pack(float re, float im) {
    const unsigned r = __float_as_uint(re) + 0x8000u;
    const unsigned i = __float_as_uint(im) + 0x8000u;
    return __builtin_amdgcn_perm(i, r, 0x07060302u);
}
__device__ __forceinline__ unsigned bf2pack2(float2 v) { return bf2pack(v.x, v.y); }

__device__ __forceinline__ float2 bf2unpack(unsigned p) {
    return make_float2(__uint_as_float(p << 16), __uint_as_float(p & 0xffff0000u));
}

// Radix-4 butterfly, in place. S=-1 forward DFT, S=+1 inverse (unscaled).
template <int S>
__device__ __forceinline__ void bfly4(float2& r0, float2& r1, float2& r2, float2& r3) {
    const float2 t0 = make_float2(r0.x + r2.x, r0.y + r2.y);
    const float2 t1 = make_float2(r0.x - r2.x, r0.y - r2.y);
    const float2 t2 = make_float2(r1.x + r3.x, r1.y + r3.y);
    const float2 t3 = make_float2(r1.x - r3.x, r1.y - r3.y);
    r0 = make_float2(t0.x + t2.x, t0.y + t2.y);
    r2 = make_float2(t0.x - t2.x, t0.y - t2.y);
    if (S < 0) {
        r1 = make_float2(t1.x + t3.y, t1.y - t3.x);   // t1 - i*t3
        r3 = make_float2(t1.x - t3.y, t1.y + t3.x);   // t1 + i*t3
    } else {
        r1 = make_float2(t1.x - t3.y, t1.y + t3.x);
        r3 = make_float2(t1.x + t3.y, t1.y - t3.x);
    }
}

// W16^(m0*k1) twiddles between the two radix-4 levels of a DFT16 (slot m0+4k1).
template <int S>
__device__ __forceinline__ void dft16_mid_twiddle(float2 a[16]) {
    const float s = (float)S;
    a[5]  = cmulc(a[5],   C16_1,  s * S16_1);                   // e1
    a[9]  = cmulc(a[9],   C16_2,  s * C16_2);                   // e2
    a[13] = cmulc(a[13],  S16_1,  s * C16_1);                   // e3
    a[6]  = cmulc(a[6],   C16_2,  s * C16_2);                   // e2
    a[10] = make_float2(-s * a[10].y, s * a[10].x);             // e4 = S*i
    a[14] = cmulc(a[14], -C16_2,  s * C16_2);                   // e6
    a[7]  = cmulc(a[7],   S16_1,  s * C16_1);                   // e3
    a[11] = cmulc(a[11], -C16_2,  s * C16_2);                   // e6
    a[15] = cmulc(a[15], -C16_1, -s * S16_1);                   // e9
}

// In-register 16-point DFT. Input: logical m at slot m. Output: logical
// A[k1+4k2] at slot 4k1+k2 (digit-swapped). All indices compile-time.
template <int S>
__device__ __forceinline__ void dft16(float2 a[16]) {
    bfly4<S>(a[0], a[4], a[8],  a[12]);
    bfly4<S>(a[1], a[5], a[9],  a[13]);
    bfly4<S>(a[2], a[6], a[10], a[14]);
    bfly4<S>(a[3], a[7], a[11], a[15]);
    dft16_mid_twiddle<S>(a);
    bfly4<S>(a[0],  a[1],  a[2],  a[3]);
    bfly4<S>(a[4],  a[5],  a[6],  a[7]);
    bfly4<S>(a[8],  a[9],  a[10], a[11]);
    bfly4<S>(a[12], a[13], a[14], a[15]);
}

// Inner radix-4 level of DFT16 when inputs m1=2,3 are zero (padded signal):
// DFT4 of (p,q,0,0) -> X[k1] = p + q*W4^(S*k1), slot c+4k1.
template <int S>
__device__ __forceinline__ void inner4_halfzero(float2 a[16]) {
#pragma unroll
    for (int c = 0; c < 4; ++c) {
        const float2 p = a[c], q = a[c + 4];
        a[c]      = make_float2(p.x + q.x, p.y + q.y);
        a[c + 8]  = make_float2(p.x - q.x, p.y - q.y);
        if (S < 0) {
            a[c + 4]  = make_float2(p.x + q.y, p.y - q.x);   // p - i*q
            a[c + 12] = make_float2(p.x - q.y, p.y + q.x);   // p + i*q
        } else {
            a[c + 4]  = make_float2(p.x - q.y, p.y + q.x);
            a[c + 12] = make_float2(p.x + q.y, p.y - q.x);
        }
    }
}

// Shared tail of the fused forward load-stage: mid twiddle, outer bfly4,
// external twiddle chain W^(-j*L) (j = tid), digit-swapped scatter to zz
// at padded span-1024 offsets pb1 + 1056*L (all compile-time).
// Cross-chunk scatter -> __syncthreads kept inside.
__device__ __forceinline__ void fwd_stage1_finish(unsigned* __restrict__ zz,
                                                  const int tid, float2 a[16]) {
    dft16_mid_twiddle<-1>(a);
    bfly4<-1>(a[0],  a[1],  a[2],  a[3]);
    bfly4<-1>(a[4],  a[5],  a[6],  a[7]);
    bfly4<-1>(a[8],  a[9],  a[10], a[11]);
    bfly4<-1>(a[12], a[13], a[14], a[15]);
    const int pb1 = tid + (tid >> 5);
    const float2 w1 = hw_cis(-(float)tid * (1.0f / 16384.0f));
    zz[pb1] = bf2pack2(a[0]);
    float2 wc = w1;
#pragma unroll
    for (int L = 1; L < 16; ++L) {
        const int P = ((L & 3) << 2) | (L >> 2);   // slot of logical L
        zz[pb1 + 1056 * L] = bf2pack2(cmul(a[P], wc));
        wc = cmul(wc, w1);
    }
    __syncthreads();
}

// One LDS radix-16 stage, span q = 1<<LQ (6 or 2) — addressing is
// WAVE-PRIVATE to chunk (tid>>6): no block barrier, caller supplies fence.
// Padded offsets: LQ=6 -> pbase + 66m ; LQ=2 -> pbase + 4m + (m>>3).
template <int S, int LQ>
__device__ __forceinline__ void fft16_stage_bf(unsigned* __restrict__ zz, const int tid) {
    const int q = 1 << LQ;
    const int j = tid & (q - 1);
    const int base = ((tid >> LQ) << (LQ + 4)) | j;
    const int pbase = base + (base >> 5);
    const float2 w1 = hw_cis((float)S * (float)j / (float)(1 << (LQ + 4)));
    float2 a[16];
    if (S < 0) {
#pragma unroll
        for (int m = 0; m < 16; ++m) {
            const int off = (LQ == 6) ? 66 * m : 4 * m + (m >> 3);
            a[m] = bf2unpack(zz[pbase + off]);
        }
        dft16<S>(a);
        zz[pbase] = bf2pack2(a[0]);
        float2 wc = w1;
#pragma unroll
        for (int L = 1; L < 16; ++L) {
            const int P = ((L & 3) << 2) | (L >> 2);
            const int off = (LQ == 6) ? 66 * L : 4 * L + (L >> 3);
            zz[pbase + off] = bf2pack2(cmul(a[P], wc));
            wc = cmul(wc, w1);
        }
    } else {
#pragma unroll
        for (int k = 0; k < 16; ++k) {
            const int off = (LQ == 6) ? 66 * k : 4 * k + (k >> 3);
            a[k] = bf2unpack(zz[pbase + off]);
        }
        float2 wc = w1;
#pragma unroll
        for (int k = 1; k < 16; ++k) { a[k] = cmul(a[k], wc); wc = cmul(wc, w1); }
        dft16<S>(a);
#pragma unroll
        for (int M = 0; M < 16; ++M) {
            const int P = ((M & 3) << 2) | (M >> 2);
            const int off = (LQ == 6) ? 66 * M : 4 * M + (M >> 3);
            zz[pbase + off] = bf2pack2(a[P]);
        }
    }
}

// Kernel A: filter spectrum -> Hws (packed bf16), digit-reversed order,
// (H + B)/N folded.
__global__ void __launch_bounds__(NTH) fftconv_filter_kernel(
        const float* __restrict__ h, const float* __restrict__ Bg,
        unsigned* __restrict__ Hws) {
    extern __shared__ unsigned zz[];
    const int d = blockIdx.x;
    const int tid = threadIdx.x;
    const int w = tid >> 6, l = tid & 63;
    const float invn = 1.0f / (float)N_FFT;
    const float Bs = Bg[d] * invn;

    // fused: load h (upper half zero) + forward stage 1 (span 1024)
    {
        const float* hrow = h + (size_t)d * L_SEQ;
        float2 a[16];
#pragma unroll
        for (int m = 0; m < 8; ++m)
            a[m] = make_float2(hrow[tid + (m << 10)], 0.0f);
        inner4_halfzero<-1>(a);
        fwd_stage1_finish(zz, tid, a);   // __syncthreads inside
    }
    fft16_stage_bf<-1, 6>(zz, tid);
    wave_fence();
    fft16_stage_bf<-1, 2>(zz, tid);
    wave_fence();

    // final forward stage (radix-4, q=1, w==1) in regs; wave-private quads
    unsigned* Hrow = Hws + (size_t)d * N_FFT;
#pragma unroll
    for (int r = 0; r < 4; ++r) {
        const int qi = (w << 8) + (r << 6) + l;
        const int pb = 4 * qi + (qi >> 3);
        float2 a0 = bf2unpack(zz[pb]);
        float2 a1 = bf2unpack(zz[pb + 1]);
        float2 a2 = bf2unpack(zz[pb + 2]);
        float2 a3 = bf2unpack(zz[pb + 3]);
        bfly4<-1>(a0, a1, a2, a3);
        ((uint4*)Hrow)[qi] = make_uint4(
            bf2pack(a0.x * invn + Bs, a0.y * invn),
            bf2pack(a1.x * invn + Bs, a1.y * invn),
            bf2pack(a2.x * invn + Bs, a2.y * invn),
            bf2pack(a3.x * invn + Bs, a3.y * invn));
    }
}

// Kernel B: y = inverse( FFT(x0 + i*x1) .* Hws ), natural-order output.
// Two block barriers total; interior phases wave-private with fences.
__global__ void __launch_bounds__(NTH) fftconv_conv_kernel(
        const float* __restrict__ x, const unsigned* __restrict__ Hws,
        float* __restrict__ y) {
    extern __shared__ unsigned zz[];
    const int d = blockIdx.x;
    const int tid = threadIdx.x;
    const int w = tid >> 6, l = tid & 63;

    const float* x0 = x + (size_t)d * L_SEQ;
    const float* x1 = x + (size_t)(D_MODEL + d) * L_SEQ;

    // fused: load x0+i*x1 (upper half zero) + forward stage 1 (span 1024)
    {
        float2 a[16];
#pragma unroll
        for (int m = 0; m < 8; ++m) {
            const int idx = tid + (m << 10);
            a[m] = make_float2(x0[idx], x1[idx]);
        }
        inner4_halfzero<-1>(a);
        fwd_stage1_finish(zz, tid, a);   // __syncthreads inside
    }

    // prefetch this wave's 16 H bins (4x uint4); vmcnt stays outstanding
    // across both interior forward stages (no barrier in the way).
    const uint4* Hp = (const uint4*)(Hws + (size_t)d * N_FFT);
    const int qbase = (w << 8) + l;
    const uint4 hp0 = Hp[qbase];
    const uint4 hp1 = Hp[qbase + 64];
    const uint4 hp2 = Hp[qbase + 128];
    const uint4 hp3 = Hp[qbase + 192];

    fft16_stage_bf<-1, 6>(zz, tid);
    wave_fence();
    fft16_stage_bf<-1, 2>(zz, tid);
    wave_fence();

    // fused middle: fwd radix-4 (w=1) -> pointwise Hws -> inv radix-4 (w=1)
#pragma unroll
    for (int r = 0; r < 4; ++r) {
        const int qi = (w << 8) + (r << 6) + l;
        const int pb = 4 * qi + (qi >> 3);
        float2 a0 = bf2unpack(zz[pb]);
        float2 a1 = bf2unpack(zz[pb + 1]);
        float2 a2 = bf2unpack(zz[pb + 2]);
        float2 a3 = bf2unpack(zz[pb + 3]);
        bfly4<-1>(a0, a1, a2, a3);
        const uint4 hp = (r == 0) ? hp0 : (r == 1) ? hp1 : (r == 2) ? hp2 : hp3;
        a0 = cmul(a0, bf2unpack(hp.x));
        a1 = cmul(a1, bf2unpack(hp.y));
        a2 = cmul(a2, bf2unpack(hp.z));
        a3 = cmul(a3, bf2unpack(hp.w));
        bfly4<+1>(a0, a1, a2, a3);
        zz[pb]     = bf2pack2(a0);
        zz[pb + 1] = bf2pack2(a1);
        zz[pb + 2] = bf2pack2(a2);
        zz[pb + 3] = bf2pack2(a3);
    }
    wave_fence();

    fft16_stage_bf<+1, 2>(zz, tid);
    wave_fence();
    fft16_stage_bf<+1, 6>(zz, tid);
    __syncthreads();   // final gather crosses chunks

    // fused: final inverse stage (span 1024) + store of outputs [0, 8192)
    {
        const int pb1 = tid + (tid >> 5);
        float2 a[16];
#pragma unroll
        for (int k = 0; k < 16; ++k) a[k] = bf2unpack(zz[pb1 + 1056 * k]);
        const float2 w1 = hw_cis((float)tid * (1.0f / 16384.0f));
        float2 wc = w1;
#pragma unroll
        for (int k = 1; k < 16; ++k) { a[k] = cmul(a[k], wc); wc = cmul(wc, w1); }
        bfly4<+1>(a[0], a[4], a[8],  a[12]);
        bfly4<+1>(a[1], a[5], a[9],  a[13]);
        bfly4<+1>(a[2], a[6], a[10], a[14]);
        bfly4<+1>(a[3], a[7], a[11], a[15]);
        dft16_mid_twiddle<+1>(a);
        float* y0 = y + (size_t)d * L_SEQ;
        float* y1 = y + (size_t)(D_MODEL + d) * L_SEQ;
        // outer bfly4, partial: only logical outputs M=g, g+4 (< 8192 kept)
#pragma unroll
        for (int g = 0; g < 4; ++g) {
            const float2 b0 = a[4*g], b1 = a[4*g+1], b2 = a[4*g+2], b3 = a[4*g+3];
            const float2 t0 = make_float2(b0.x + b2.x, b0.y + b2.y);
            const float2 t1 = make_float2(b0.x - b2.x, b0.y - b2.y);
            const float2 t2 = make_float2(b1.x + b3.x, b1.y + b3.y);
            const float2 t3 = make_float2(b1.x - b3.x, b1.y - b3.y);
            const float2 r0 = make_float2(t0.x + t2.x, t0.y + t2.y);   // M=g
            const float2 r1 = make_float2(t1.x - t3.y, t1.y + t3.x);   // M=g+4 (S=+1)
            const int q0 = tid + (g << 10);
            const int q1 = tid + ((g + 4) << 10);
            y0[q0] = r0.x; y1[q0] = r0.y;
            y0[q1] = r1.x; y1[q1] = r1.y;
        }
    }
}

extern "C" void kernel_launch(void* const* d_in, const int* in_sizes, int n_in,
                              void* d_out, int out_size, void* d_ws, size_t ws_size,
                              hipStream_t stream) {
    const float* h = (const float*)d_in[0];   // (1024, 8192)
    const float* x = (const float*)d_in[1];   // (2, 1024, 8192)
    const float* B = (const float*)d_in[2];   // (1024, 1)
    float* y = (float*)d_out;                 // (2, 1024, 8192)
    unsigned* Hws = (unsigned*)d_ws;          // 1024 x 16384 packed bf16 = 67 MB

    const size_t lds_bytes = (size_t)LDS_U32 * sizeof(unsigned);  // 67.6 KB

    fftconv_filter_kernel<<<dim3(D_MODEL), dim3(NTH), lds_bytes, stream>>>(h, B, Hws);
    fftconv_conv_kernel<<<dim3(D_MODEL), dim3(NTH), lds_bytes, stream>>>(x, Hws, y);
}

// Round 20
// 87.466 us; speedup vs baseline: 1.2316x; 1.0581x over previous
//
#include <hip/hip_runtime.h>

// FFTConv: y[b,d,:] = (h[d] (*) x[b,d])[0:L] + x[b,d]*B[d]
// d_model=1024, L=8192, batch=2, fp32. N=16384 = 16*16*16*4.
// TWO kernels (R9/R10: fusing spills past the immovable 64-VGPR cap).
// bf16-packed LDS zz (R11), R15 structure, perm-pack (R17), padded LDS
// layout P(i)=i+(i>>5) with compile-time ds offsets (R18: VGPR 60->36).
// R19: fence-lite. The interior stages are wave-private; same-wave LDS ops
// execute in issue order (in-order DS pipe), and the compiler auto-inserts
// lgkmcnt before consuming ds_read results. So the runtime drain
// (s_waitcnt lgkmcnt(0)) + sched_barrier(0) at each stage boundary only
// cost stall cycles + pinned scheduling. Replaced with a pure compiler
// memory barrier. Block barriers remain only at the two cross-chunk points.
//   A: Hws[d] = digit-rev spectrum( (FFT(pad(h[d])) + B[d]) / N ), bf16 pairs
//   B: y = stage-exact-inverse( FFT(pad(x0+i*x1)) .* Hws ), natural order

#define L_SEQ   8192
#define N_FFT   16384
#define D_MODEL 1024
#define NTH     1024
#define LDS_U32 (N_FFT + (N_FFT >> 5))   // 16896 u32 = 67.6 KB

// W16 twiddle constants
#define C16_1 0.92387953251128675613f
#define S16_1 0.38268343236508977173f
#define C16_2 0.70710678118654752440f

// Compiler-only LDS ordering barrier: prevents the compiler from moving
// LDS accesses across stage boundaries. NO runtime drain — same-wave DS
// ops are in-order in HW; lgkmcnt for read-results is auto-inserted.
__device__ __forceinline__ void compiler_fence() {
    asm volatile("" ::: "memory");
}

__device__ __forceinline__ float2 cmul(float2 a, float2 b) {
    return make_float2(a.x * b.x - a.y * b.y, a.x * b.y + a.y * b.x);
}
__device__ __forceinline__ float2 cmulc(float2 a, float re, float im) {
    return make_float2(a.x * re - a.y * im, a.x * im + a.y * re);
}

// Hardware sin/cos of (2*pi*rev); exact-argument for rev = j * 2^-k.
// Used ONCE per stage (w1 seed); powers via cmul chain (full-rate VALU;
// R16 proved per-power TRANS-pipe cis regresses — quarter-rate pipe).
__device__ __forceinline__ float2 hw_cis(float rev) {
    return make_float2(__builtin_amdgcn_cosf(rev), __builtin_amdgcn_sinf(rev));
}

// Pack two floats as bf16 (round-half-up) into one uint: re -> low half,
// im -> high half. 2 adds + 1 v_perm_b32 (selector 0x07060302, src0=im,
// src1=re). Schedulable intrinsic (R12's inline-asm variant blocked sched).
__device__ __forceinline__ unsigned bf2pack(float re, float im) {
    const unsigned r = __float_as_uint(re) + 0x8000u;
    const unsigned i = __float_as_uint(im) + 0x8000u;
    return __builtin_amdgcn_perm(i, r, 0x07060302u);
}
__device__ __forceinline__ unsigned bf2pack2(float2 v) { return bf2pack(v.x, v.y); }

__device__ __forceinline__ float2 bf2unpack(unsigned p) {
    return make_float2(__uint_as_float(p << 16), __uint_as_float(p & 0xffff0000u));
}

// Radix-4 butterfly, in place. S=-1 forward DFT, S=+1 inverse (unscaled).
template <int S>
__device__ __forceinline__ void bfly4(float2& r0, float2& r1, float2& r2, float2& r3) {
    const float2 t0 = make_float2(r0.x + r2.x, r0.y + r2.y);
    const float2 t1 = make_float2(r0.x - r2.x, r0.y - r2.y);
    const float2 t2 = make_float2(r1.x + r3.x, r1.y + r3.y);
    const float2 t3 = make_float2(r1.x - r3.x, r1.y - r3.y);
    r0 = make_float2(t0.x + t2.x, t0.y + t2.y);
    r2 = make_float2(t0.x - t2.x, t0.y - t2.y);
    if (S < 0) {
        r1 = make_float2(t1.x + t3.y, t1.y - t3.x);   // t1 - i*t3
        r3 = make_float2(t1.x - t3.y, t1.y + t3.x);   // t1 + i*t3
    } else {
        r1 = make_float2(t1.x - t3.y, t1.y + t3.x);
        r3 = make_float2(t1.x + t3.y, t1.y - t3.x);
    }
}

// W16^(m0*k1) twiddles between the two radix-4 levels of a DFT16 (slot m0+4k1).
template <int S>
__device__ __forceinline__ void dft16_mid_twiddle(float2 a[16]) {
    const float s = (float)S;
    a[5]  = cmulc(a[5],   C16_1,  s * S16_1);                   // e1
    a[9]  = cmulc(a[9],   C16_2,  s * C16_2);                   // e2
    a[13] = cmulc(a[13],  S16_1,  s * C16_1);                   // e3
    a[6]  = cmulc(a[6],   C16_2,  s * C16_2);                   // e2
    a[10] = make_float2(-s * a[10].y, s * a[10].x);             // e4 = S*i
    a[14] = cmulc(a[14], -C16_2,  s * C16_2);                   // e6
    a[7]  = cmulc(a[7],   S16_1,  s * C16_1);                   // e3
    a[11] = cmulc(a[11], -C16_2,  s * C16_2);                   // e6
    a[15] = cmulc(a[15], -C16_1, -s * S16_1);                   // e9
}

// In-register 16-point DFT. Input: logical m at slot m. Output: logical
// A[k1+4k2] at slot 4k1+k2 (digit-swapped). All indices compile-time.
template <int S>
__device__ __forceinline__ void dft16(float2 a[16]) {
    bfly4<S>(a[0], a[4], a[8],  a[12]);
    bfly4<S>(a[1], a[5], a[9],  a[13]);
    bfly4<S>(a[2], a[6], a[10], a[14]);
    bfly4<S>(a[3], a[7], a[11], a[15]);
    dft16_mid_twiddle<S>(a);
    bfly4<S>(a[0],  a[1],  a[2],  a[3]);
    bfly4<S>(a[4],  a[5],  a[6],  a[7]);
    bfly4<S>(a[8],  a[9],  a[10], a[11]);
    bfly4<S>(a[12], a[13], a[14], a[15]);
}

// Inner radix-4 level of DFT16 when inputs m1=2,3 are zero (padded signal):
// DFT4 of (p,q,0,0) -> X[k1] = p + q*W4^(S*k1), slot c+4k1.
template <int S>
__device__ __forceinline__ void inner4_halfzero(float2 a[16]) {
#pragma unroll
    for (int c = 0; c < 4; ++c) {
        const float2 p = a[c], q = a[c + 4];
        a[c]      = make_float2(p.x + q.x, p.y + q.y);
        a[c + 8]  = make_float2(p.x - q.x, p.y - q.y);
        if (S < 0) {
            a[c + 4]  = make_float2(p.x + q.y, p.y - q.x);   // p - i*q
            a[c + 12] = make_float2(p.x - q.y, p.y + q.x);   // p + i*q
        } else {
            a[c + 4]  = make_float2(p.x - q.y, p.y + q.x);
            a[c + 12] = make_float2(p.x + q.y, p.y - q.x);
        }
    }
}

// Shared tail of the fused forward load-stage: mid twiddle, outer bfly4,
// external twiddle chain W^(-j*L) (j = tid), digit-swapped scatter to zz
// at padded span-1024 offsets pb1 + 1056*L (all compile-time).
// Cross-chunk scatter -> __syncthreads kept inside.
__device__ __forceinline__ void fwd_stage1_finish(unsigned* __restrict__ zz,
                                                  const int tid, float2 a[16]) {
    dft16_mid_twiddle<-1>(a);
    bfly4<-1>(a[0],  a[1],  a[2],  a[3]);
    bfly4<-1>(a[4],  a[5],  a[6],  a[7]);
    bfly4<-1>(a[8],  a[9],  a[10], a[11]);
    bfly4<-1>(a[12], a[13], a[14], a[15]);
    const int pb1 = tid + (tid >> 5);
    const float2 w1 = hw_cis(-(float)tid * (1.0f / 16384.0f));
    zz[pb1] = bf2pack2(a[0]);
    float2 wc = w1;
#pragma unroll
    for (int L = 1; L < 16; ++L) {
        const int P = ((L & 3) << 2) | (L >> 2);   // slot of logical L
        zz[pb1 + 1056 * L] = bf2pack2(cmul(a[P], wc));
        wc = cmul(wc, w1);
    }
    __syncthreads();
}

// One LDS radix-16 stage, span q = 1<<LQ (6 or 2) — addressing is
// WAVE-PRIVATE to chunk (tid>>6): no block barrier needed.
// Padded offsets: LQ=6 -> pbase + 66m ; LQ=2 -> pbase + 4m + (m>>3).
template <int S, int LQ>
__device__ __forceinline__ void fft16_stage_bf(unsigned* __restrict__ zz, const int tid) {
    const int q = 1 << LQ;
    const int j = tid & (q - 1);
    const int base = ((tid >> LQ) << (LQ + 4)) | j;
    const int pbase = base + (base >> 5);
    const float2 w1 = hw_cis((float)S * (float)j / (float)(1 << (LQ + 4)));
    float2 a[16];
    if (S < 0) {
#pragma unroll
        for (int m = 0; m < 16; ++m) {
            const int off = (LQ == 6) ? 66 * m : 4 * m + (m >> 3);
            a[m] = bf2unpack(zz[pbase + off]);
        }
        dft16<S>(a);
        zz[pbase] = bf2pack2(a[0]);
        float2 wc = w1;
#pragma unroll
        for (int L = 1; L < 16; ++L) {
            const int P = ((L & 3) << 2) | (L >> 2);
            const int off = (LQ == 6) ? 66 * L : 4 * L + (L >> 3);
            zz[pbase + off] = bf2pack2(cmul(a[P], wc));
            wc = cmul(wc, w1);
        }
    } else {
#pragma unroll
        for (int k = 0; k < 16; ++k) {
            const int off = (LQ == 6) ? 66 * k : 4 * k + (k >> 3);
            a[k] = bf2unpack(zz[pbase + off]);
        }
        float2 wc = w1;
#pragma unroll
        for (int k = 1; k < 16; ++k) { a[k] = cmul(a[k], wc); wc = cmul(wc, w1); }
        dft16<S>(a);
#pragma unroll
        for (int M = 0; M < 16; ++M) {
            const int P = ((M & 3) << 2) | (M >> 2);
            const int off = (LQ == 6) ? 66 * M : 4 * M + (M >> 3);
            zz[pbase + off] = bf2pack2(a[P]);
        }
    }
}

// Kernel A: filter spectrum -> Hws (packed bf16), digit-reversed order,
// (H + B)/N folded.
__global__ void __launch_bounds__(NTH) fftconv_filter_kernel(
        const float* __restrict__ h, const float* __restrict__ Bg,
        unsigned* __restrict__ Hws) {
    extern __shared__ unsigned zz[];
    const int d = blockIdx.x;
    const int tid = threadIdx.x;
    const int w = tid >> 6, l = tid & 63;
    const float invn = 1.0f / (float)N_FFT;
    const float Bs = Bg[d] * invn;

    // fused: load h (upper half zero) + forward stage 1 (span 1024)
    {
        const float* hrow = h + (size_t)d * L_SEQ;
        float2 a[16];
#pragma unroll
        for (int m = 0; m < 8; ++m)
            a[m] = make_float2(hrow[tid + (m << 10)], 0.0f);
        inner4_halfzero<-1>(a);
        fwd_stage1_finish(zz, tid, a);   // __syncthreads inside
    }
    fft16_stage_bf<-1, 6>(zz, tid);
    compiler_fence();
    fft16_stage_bf<-1, 2>(zz, tid);
    compiler_fence();

    // final forward stage (radix-4, q=1, w==1) in regs; wave-private quads
    unsigned* Hrow = Hws + (size_t)d * N_FFT;
#pragma unroll
    for (int r = 0; r < 4; ++r) {
        const int qi = (w << 8) + (r << 6) + l;
        const int pb = 4 * qi + (qi >> 3);
        float2 a0 = bf2unpack(zz[pb]);
        float2 a1 = bf2unpack(zz[pb + 1]);
        float2 a2 = bf2unpack(zz[pb + 2]);
        float2 a3 = bf2unpack(zz[pb + 3]);
        bfly4<-1>(a0, a1, a2, a3);
        ((uint4*)Hrow)[qi] = make_uint4(
            bf2pack(a0.x * invn + Bs, a0.y * invn),
            bf2pack(a1.x * invn + Bs, a1.y * invn),
            bf2pack(a2.x * invn + Bs, a2.y * invn),
            bf2pack(a3.x * invn + Bs, a3.y * invn));
    }
}

// Kernel B: y = inverse( FFT(x0 + i*x1) .* Hws ), natural-order output.
// Two block barriers total; interior phases wave-private.
__global__ void __launch_bounds__(NTH) fftconv_conv_kernel(
        const float* __restrict__ x, const unsigned* __restrict__ Hws,
        float* __restrict__ y) {
    extern __shared__ unsigned zz[];
    const int d = blockIdx.x;
    const int tid = threadIdx.x;
    const int w = tid >> 6, l = tid & 63;

    const float* x0 = x + (size_t)d * L_SEQ;
    const float* x1 = x + (size_t)(D_MODEL + d) * L_SEQ;

    // fused: load x0+i*x1 (upper half zero) + forward stage 1 (span 1024)
    {
        float2 a[16];
#pragma unroll
        for (int m = 0; m < 8; ++m) {
            const int idx = tid + (m << 10);
            a[m] = make_float2(x0[idx], x1[idx]);
        }
        inner4_halfzero<-1>(a);
        fwd_stage1_finish(zz, tid, a);   // __syncthreads inside
    }

    // prefetch this wave's 16 H bins (4x uint4); vmcnt stays outstanding
    // across both interior forward stages (no barrier in the way).
    const uint4* Hp = (const uint4*)(Hws + (size_t)d * N_FFT);
    const int qbase = (w << 8) + l;
    const uint4 hp0 = Hp[qbase];
    const uint4 hp1 = Hp[qbase + 64];
    const uint4 hp2 = Hp[qbase + 128];
    const uint4 hp3 = Hp[qbase + 192];

    fft16_stage_bf<-1, 6>(zz, tid);
    compiler_fence();
    fft16_stage_bf<-1, 2>(zz, tid);
    compiler_fence();

    // fused middle: fwd radix-4 (w=1) -> pointwise Hws -> inv radix-4 (w=1)
#pragma unroll
    for (int r = 0; r < 4; ++r) {
        const int qi = (w << 8) + (r << 6) + l;
        const int pb = 4 * qi + (qi >> 3);
        float2 a0 = bf2unpack(zz[pb]);
        float2 a1 = bf2unpack(zz[pb + 1]);
        float2 a2 = bf2unpack(zz[pb + 2]);
        float2 a3 = bf2unpack(zz[pb + 3]);
        bfly4<-1>(a0, a1, a2, a3);
        const uint4 hp = (r == 0) ? hp0 : (r == 1) ? hp1 : (r == 2) ? hp2 : hp3;
        a0 = cmul(a0, bf2unpack(hp.x));
        a1 = cmul(a1, bf2unpack(hp.y));
        a2 = cmul(a2, bf2unpack(hp.z));
        a3 = cmul(a3, bf2unpack(hp.w));
        bfly4<+1>(a0, a1, a2, a3);
        zz[pb]     = bf2pack2(a0);
        zz[pb + 1] = bf2pack2(a1);
        zz[pb + 2] = bf2pack2(a2);
        zz[pb + 3] = bf2pack2(a3);
    }
    compiler_fence();

    fft16_stage_bf<+1, 2>(zz, tid);
    compiler_fence();
    fft16_stage_bf<+1, 6>(zz, tid);
    __syncthreads();   // final gather crosses chunks

    // fused: final inverse stage (span 1024) + store of outputs [0, 8192)
    {
        const int pb1 = tid + (tid >> 5);
        float2 a[16];
#pragma unroll
        for (int k = 0; k < 16; ++k) a[k] = bf2unpack(zz[pb1 + 1056 * k]);
        const float2 w1 = hw_cis((float)tid * (1.0f / 16384.0f));
        float2 wc = w1;
#pragma unroll
        for (int k = 1; k < 16; ++k) { a[k] = cmul(a[k], wc); wc = cmul(wc, w1); }
        bfly4<+1>(a[0], a[4], a[8],  a[12]);
        bfly4<+1>(a[1], a[5], a[9],  a[13]);
        bfly4<+1>(a[2], a[6], a[10], a[14]);
        bfly4<+1>(a[3], a[7], a[11], a[15]);
        dft16_mid_twiddle<+1>(a);
        float* y0 = y + (size_t)d * L_SEQ;
        float* y1 = y + (size_t)(D_MODEL + d) * L_SEQ;
        // outer bfly4, partial: only logical outputs M=g, g+4 (< 8192 kept)
#pragma unroll
        for (int g = 0; g < 4; ++g) {
            const float2 b0 = a[4*g], b1 = a[4*g+1], b2 = a[4*g+2], b3 = a[4*g+3];
            const float2 t0 = make_float2(b0.x + b2.x, b0.y + b2.y);
            const float2 t1 = make_float2(b0.x - b2.x, b0.y - b2.y);
            const float2 t2 = make_float2(b1.x + b3.x, b1.y + b3.y);
            const float2 t3 = make_float2(b1.x - b3.x, b1.y - b3.y);
            const float2 r0 = make_float2(t0.x + t2.x, t0.y + t2.y);   // M=g
            const float2 r1 = make_float2(t1.x - t3.y, t1.y + t3.x);   // M=g+4 (S=+1)
            const int q0 = tid + (g << 10);
            const int q1 = tid + ((g + 4) << 10);
            y0[q0] = r0.x; y1[q0] = r0.y;
            y0[q1] = r1.x; y1[q1] = r1.y;
        }
    }
}

extern "C" void kernel_launch(void* const* d_in, const int* in_sizes, int n_in,
                              void* d_out, int out_size, void* d_ws, size_t ws_size,
                              hipStream_t stream) {
    const float* h = (const float*)d_in[0];   // (1024, 8192)
    const float* x = (const float*)d_in[1];   // (2, 1024, 8192)
    const float* B = (const float*)d_in[2];   // (1024, 1)
    float* y = (float*)d_out;                 // (2, 1024, 8192)
    unsigned* Hws = (unsigned*)d_ws;          // 1024 x 16384 packed bf16 = 67 MB

    const size_t lds_bytes = (size_t)LDS_U32 * sizeof(unsigned);  // 67.6 KB

    fftconv_filter_kernel<<<dim3(D_MODEL), dim3(NTH), lds_bytes, stream>>>(h, B, Hws);
    fftconv_conv_kernel<<<dim3(D_MODEL), dim3(NTH), lds_bytes, stream>>>(x, Hws, y);
}